// Round 4
// baseline (294.558 us; speedup 1.0000x reference)
//
#include <hip/hip_runtime.h>

// Problem constants (B=16, C=128, H=W=64, N=4096, M=256, K=9, OUT=128)
#define NB   16
#define NC   128
#define NN   4096
#define NM   256
#define NK   9
#define NO   128

#define DELTA 0.0078125f   // candidate margin: 4x worst-case fma-vs-np key bound

// round(linspace(0, 63, 16)) -- identical under f32 (jax) and f64 (np) linspace
__device__ __constant__ int d_grid16[16] = {0,4,8,13,17,21,25,29,34,38,42,46,50,55,59,63};

// ---------------------------------------------------------------------------
// K0: transpose w (O,C,K) -> Wr (C,K,O) for coalesced GEMM B-operand
__global__ __launch_bounds__(256) void k_wr(const float* __restrict__ w,
                                            float* __restrict__ Wr) {
    int f = blockIdx.x * 256 + threadIdx.x;         // f < 128*9*128 = 147456
    int o = f & 127;
    int k = (f >> 7) % 9;
    int c = f / 1152;
    Wr[f] = w[o * 1152 + c * 9 + k];
}

// ---------------------------------------------------------------------------
// K1: gather sample features xs[b][c][m] = x[b][c][pix(m)]
__global__ __launch_bounds__(256) void k_gather(const float* __restrict__ x,
                                                float* __restrict__ xs) {
    int bc = blockIdx.x;                            // b*128 + c
    int m  = threadIdx.x;                           // 0..255
    int pix = d_grid16[m >> 4] * 64 + d_grid16[m & 15];
    xs[bc * NM + m] = x[bc * NN + pix];
}

// ---------------------------------------------------------------------------
// K1b: m2[b][m] = sum_c xs^2 -- bit-exact np f32: sequential c, mul+add (no fma)
__global__ __launch_bounds__(256) void k_m2(const float* __restrict__ xs,
                                            float* __restrict__ m2) {
    #pragma clang fp contract(off)
    int f = blockIdx.x * 256 + threadIdx.x;         // < 4096
    int b = f >> 8, m = f & 255;
    const float* p = xs + (size_t)b * NC * NM + m;
    float a = 0.f;
    #pragma unroll 4
    for (int c = 0; c < NC; ++c) { float v = p[c * NM]; a = __fadd_rn(a, __fmul_rn(v, v)); }
    m2[f] = a;
}

// ---------------------------------------------------------------------------
// K2: G[b][m][k][o] = sum_c xs[b][c][m] * Wr[c][k][o]   (fp32 fma - output path)
__global__ __launch_bounds__(256) void k_g(const float* __restrict__ xs,
                                           const float* __restrict__ Wr,
                                           float* __restrict__ G) {
    __shared__ float xsl[64 * 64];    // [cc][mm]
    __shared__ float wl[64 * 128];    // [cc][o]
    int kk = blockIdx.x, mt = blockIdx.y, b = blockIdx.z;
    int t = threadIdx.x;
    int to = t & 31, tmm = t >> 5;
    float acc[8][4] = {};
    for (int c0 = 0; c0 < NC; c0 += 64) {
        __syncthreads();
        #pragma unroll
        for (int it = 0; it < 16; ++it) {
            int f = it * 256 + t;
            int cc = f >> 6, mm = f & 63;
            xsl[f] = xs[((size_t)b * NC + c0 + cc) * NM + mt * 64 + mm];
        }
        #pragma unroll
        for (int it = 0; it < 32; ++it) {
            int f = it * 256 + t;
            int cc = f >> 7, o = f & 127;
            wl[f] = Wr[(size_t)(c0 + cc) * 1152 + kk * 128 + o];
        }
        __syncthreads();
        for (int cc = 0; cc < 64; ++cc) {
            const float4 a0 = *(const float4*)&xsl[cc * 64 + tmm * 8];
            const float4 a1 = *(const float4*)&xsl[cc * 64 + tmm * 8 + 4];
            float av[8] = {a0.x, a0.y, a0.z, a0.w, a1.x, a1.y, a1.z, a1.w};
            float2 w0 = *(const float2*)&wl[cc * 128 + 2 * to];
            float2 w1 = *(const float2*)&wl[cc * 128 + 64 + 2 * to];
            float wv[4] = {w0.x, w0.y, w1.x, w1.y};
            #pragma unroll
            for (int i = 0; i < 8; ++i)
                #pragma unroll
                for (int j = 0; j < 4; ++j)
                    acc[i][j] = fmaf(av[i], wv[j], acc[i][j]);
        }
    }
    #pragma unroll
    for (int i = 0; i < 8; ++i) {
        size_t base = (((size_t)(b * NM + mt * 64 + tmm * 8 + i) * NK + kk) << 7);
        *(float2*)&G[base + 2 * to]      = make_float2(acc[i][0], acc[i][1]);
        *(float2*)&G[base + 64 + 2 * to] = make_float2(acc[i][2], acc[i][3]);
    }
}

// ---------------------------------------------------------------------------
// K3 pass 1: FMA dots + approx top-9 -> threshold -> candidate list (<=16/token).
// grid (128 tiles, 16 b), 256 thr; tile = 32 tokens x 256 samples.
__device__ inline unsigned long long shfl_xor_u64(unsigned long long v, int m) {
    int lo = __shfl_xor((int)(v & 0xFFFFFFFFull), m, 64);
    int hi = __shfl_xor((int)(v >> 32), m, 64);
    return ((unsigned long long)(unsigned)hi << 32) | (unsigned)lo;
}

__global__ __launch_bounds__(256) void k_sel(const float* __restrict__ x,
                                             const float* __restrict__ xs,
                                             const float* __restrict__ m2,
                                             unsigned short* __restrict__ cand) {
    // staging: x1 tile [0,1024): [cc][nn] 32x32 ; xs tile [1024,9216): [cc][m] 32x256
    // phase B reuses sm as float keys [32][258] = 8256 floats <= 9216
    __shared__ float sm[9216];
    __shared__ float m2l[256];
    __shared__ int   cntl[32];
    int b = blockIdx.y, n0 = blockIdx.x * 32;
    int t = threadIdx.x;
    int tm = t & 31, tn = t >> 5;     // m-lane (8 m's), token-group (4 tokens)
    m2l[t] = m2[b * NM + t];
    if (t < 32) cntl[t] = 0;
    float acc[4][8];
    #pragma unroll
    for (int i = 0; i < 4; ++i)
        #pragma unroll
        for (int j = 0; j < 8; ++j) acc[i][j] = 0.f;

    for (int c0 = 0; c0 < NC; c0 += 32) {
        __syncthreads();
        {   // x1 tile: 1024 floats = 256 float4, one per thread
            int cc = t >> 3, nn4 = (t & 7) * 4;
            *(float4*)&sm[cc * 32 + nn4] =
                *(const float4*)&x[((size_t)b * NC + c0 + cc) * NN + n0 + nn4];
        }
        #pragma unroll
        for (int it = 0; it < 8; ++it) {            // xs tile: 2048 float4
            int f4 = it * 256 + t;
            int cc = f4 >> 6, mm4 = (f4 & 63) * 4;
            *(float4*)&sm[1024 + cc * 256 + mm4] =
                *(const float4*)&xs[((size_t)b * NC + c0 + cc) * NM + mm4];
        }
        __syncthreads();
        for (int cc = 0; cc < 32; ++cc) {
            const float4 a4 = *(const float4*)&sm[cc * 32 + tn * 4];
            float av[4] = {a4.x, a4.y, a4.z, a4.w};
            float2 s0 = *(const float2*)&sm[1024 + cc * 256 + 2 * tm];
            float2 s1 = *(const float2*)&sm[1024 + cc * 256 + 64 + 2 * tm];
            float2 s2 = *(const float2*)&sm[1024 + cc * 256 + 128 + 2 * tm];
            float2 s3 = *(const float2*)&sm[1024 + cc * 256 + 192 + 2 * tm];
            float sv[8] = {s0.x, s0.y, s1.x, s1.y, s2.x, s2.y, s3.x, s3.y};
            #pragma unroll
            for (int i = 0; i < 4; ++i)
                #pragma unroll
                for (int j = 0; j < 8; ++j)
                    acc[i][j] = fmaf(av[i], sv[j], acc[i][j]);   // fast path: fma OK
        }
    }
    __syncthreads();
    // ---- phase B: float keys (m2 - 2*dot; n2 dropped -- per-token constant) ----
    int   mj[8];
    float m2v[8];
    #pragma unroll
    for (int j = 0; j < 8; ++j) { mj[j] = (j >> 1) * 64 + 2 * tm + (j & 1); m2v[j] = m2l[mj[j]]; }
    #pragma unroll
    for (int i = 0; i < 4; ++i) {
        int n = tn * 4 + i;
        #pragma unroll
        for (int j = 0; j < 8; ++j)
            sm[n * 258 + mj[j]] = fmaf(-2.f, acc[i][j], m2v[j]);
    }
    __syncthreads();
    // ---- phase C: approx top-9 (8 lanes/token) -> theta; then threshold-collect ----
    {
        int n = t >> 3, q = t & 7;
        unsigned long long bk[9];
        #pragma unroll
        for (int j = 0; j < 9; ++j) bk[j] = ~0ull;
        for (int i = 0; i < 32; ++i) {
            int m = q + 8 * i;
            unsigned u = __float_as_uint(sm[n * 258 + m]);
            u = (u & 0x80000000u) ? ~u : (u | 0x80000000u);
            unsigned long long v = ((unsigned long long)u << 32) | (unsigned)m;
            if (v < bk[8]) {
                #pragma unroll
                for (int j = 0; j < 9; ++j) {
                    unsigned long long t0 = bk[j];
                    bool c = v < t0;
                    bk[j] = c ? v : t0;
                    v     = c ? t0 : v;
                }
            }
        }
        #pragma unroll
        for (int rr = 1; rr <= 4; rr <<= 1) {
            unsigned long long pv[9];
            #pragma unroll
            for (int j = 0; j < 9; ++j) pv[j] = shfl_xor_u64(bk[j], rr);
            #pragma unroll
            for (int j = 0; j < 9; ++j) {
                unsigned long long v = pv[j];
                if (v >= bk[8]) break;
                #pragma unroll
                for (int jj = 0; jj < 9; ++jj) {
                    unsigned long long t0 = bk[jj];
                    bool c = v < t0;
                    bk[jj] = c ? v : t0;
                    v      = c ? t0 : v;
                }
            }
        }
        // theta from approx 9th key (all 8 lanes agree after butterfly)
        unsigned u9 = (unsigned)(bk[8] >> 32);
        u9 = (u9 & 0x80000000u) ? (u9 & 0x7FFFFFFFu) : ~u9;
        float theta = __uint_as_float(u9) + DELTA;
        size_t tokbase = (size_t)(b * NN + n0 + n) * 16;
        for (int i = 0; i < 32; ++i) {
            int m = q + 8 * i;
            if (sm[n * 258 + m] <= theta) {
                int pos = atomicAdd(&cntl[n], 1);
                if (pos < 16) cand[tokbase + pos] = (unsigned short)m;
            }
        }
        __syncthreads();
        if (q == 0) {
            int c = cntl[n]; if (c > 16) c = 16;
            for (int s = c; s < 16; ++s) cand[tokbase + s] = 0xFFFFu;
        }
    }
}

// ---------------------------------------------------------------------------
// K3 pass 2: np-bit-exact re-rank of <=16 candidates/token.
//   dot/n2: sequential c=0..127, acc = fadd(acc, fmul(.)); key = fsub(fadd(n2,m2), fmul(2,dot))
// grid (128 tiles, 16 b), 256 thr; 32 tokens/block, 8 lanes/token, 2 cands/lane.
__global__ __launch_bounds__(256) void k_ref(const float* __restrict__ x,
                                             const float* __restrict__ xs,
                                             const float* __restrict__ m2,
                                             const unsigned short* __restrict__ cand,
                                             int* __restrict__ idx) {
    #pragma clang fp contract(off)
    __shared__ float xsl[32 * 256];   // [cc][m] 32 KB
    __shared__ float x1l[32 * 32];    // [cc][r]  4 KB
    __shared__ float m2l[256];
    __shared__ unsigned long long pairs[32 * 16];
    int b = blockIdx.y, n0 = blockIdx.x * 32;
    int t = threadIdx.x;
    m2l[t] = m2[b * NM + t];
    int r = t >> 3, q = t & 7;        // token row, lane
    int n = n0 + r;
    size_t tokbase = (size_t)(b * NN + n) * 16;
    int mA = cand[tokbase + q];
    int mB = cand[tokbase + 8 + q];
    bool vA = (mA != 0xFFFF), vB = (mB != 0xFFFF);
    int mAx = vA ? mA : 0, mBx = vB ? mB : 0;
    float dotA = 0.f, dotB = 0.f, n2 = 0.f;
    for (int c0 = 0; c0 < NC; c0 += 32) {
        __syncthreads();
        {   // x1 chunk: 1024 floats = 256 float4
            int cc = t >> 3, nn4 = (t & 7) * 4;
            *(float4*)&x1l[cc * 32 + nn4] =
                *(const float4*)&x[((size_t)b * NC + c0 + cc) * NN + n0 + nn4];
        }
        #pragma unroll
        for (int it = 0; it < 8; ++it) {            // xs chunk: 2048 float4
            int f4 = it * 256 + t;
            int cc = f4 >> 6, mm4 = (f4 & 63) * 4;
            *(float4*)&xsl[cc * 256 + mm4] =
                *(const float4*)&xs[((size_t)b * NC + c0 + cc) * NM + mm4];
        }
        __syncthreads();
        for (int cc = 0; cc < 32; ++cc) {           // ascending c: np order
            float xv = x1l[cc * 32 + r];
            n2   = __fadd_rn(n2,   __fmul_rn(xv, xv));
            dotA = __fadd_rn(dotA, __fmul_rn(xv, xsl[cc * 256 + mAx]));
            dotB = __fadd_rn(dotB, __fmul_rn(xv, xsl[cc * 256 + mBx]));
        }
    }
    // exact np keys -> sortable pairs
    unsigned long long pA = ~0ull, pB = ~0ull;
    if (vA) {
        float key = __fsub_rn(__fadd_rn(n2, m2l[mAx]), __fmul_rn(2.f, dotA));
        unsigned u = __float_as_uint(key);
        u = (u & 0x80000000u) ? ~u : (u | 0x80000000u);
        pA = ((unsigned long long)u << 32) | (unsigned)mAx;
    }
    if (vB) {
        float key = __fsub_rn(__fadd_rn(n2, m2l[mBx]), __fmul_rn(2.f, dotB));
        unsigned u = __float_as_uint(key);
        u = (u & 0x80000000u) ? ~u : (u | 0x80000000u);
        pB = ((unsigned long long)u << 32) | (unsigned)mBx;
    }
    pairs[r * 16 + q]     = pA;
    pairs[r * 16 + 8 + q] = pB;
    __syncthreads();
    size_t obase = (size_t)(b * NN + n) * NK;
    if (vA) {
        int rank = 0;
        #pragma unroll
        for (int j = 0; j < 16; ++j) rank += (pairs[r * 16 + j] < pA);
        if (rank < 9) idx[obase + rank] = mAx;
    }
    if (vB) {
        int rank = 0;
        #pragma unroll
        for (int j = 0; j < 16; ++j) rank += (pairs[r * 16 + j] < pB);
        if (rank < 9) idx[obase + rank] = mBx;
    }
}

// ---------------------------------------------------------------------------
// K4: out[b][o][n] = bias[o] + sum_k G[b][idx[b,n,k]][k][o]
__global__ __launch_bounds__(256) void k_out(const float* __restrict__ G,
                                             const int* __restrict__ idx,
                                             const float* __restrict__ bias,
                                             float* __restrict__ out) {
    __shared__ float S[64 * 129];
    __shared__ int   idxl[576];
    __shared__ float biasl[128];
    int b = blockIdx.y, n0 = blockIdx.x * 64;
    int t = threadIdx.x;
    if (t < 128) biasl[t] = bias[t];
    for (int f = t; f < 576; f += 256) idxl[f] = idx[(size_t)(b * NN + n0) * NK + f];
    __syncthreads();
    int o = t & 127, half = t >> 7;
    for (int p = 0; p < 32; ++p) {
        int n = p * 2 + half;
        float a = biasl[o];
        #pragma unroll
        for (int k = 0; k < 9; ++k) {
            int m = idxl[n * 9 + k];
            a += G[(((size_t)(b * NM + m)) * NK + k) * 128 + o];
        }
        S[n * 129 + o] = a;
    }
    __syncthreads();
    int nn = t & 63, ob = t >> 6;
    for (int p = 0; p < 32; ++p) {
        int o2 = p * 4 + ob;
        out[((size_t)(b * NO + o2)) * NN + n0 + nn] = S[nn * 129 + o2];
    }
}

// ---------------------------------------------------------------------------
extern "C" void kernel_launch(void* const* d_in, const int* in_sizes, int n_in,
                              void* d_out, int out_size, void* d_ws, size_t ws_size,
                              hipStream_t stream) {
    const float* x    = (const float*)d_in[0];   // (16,128,64,64)
    const float* w    = (const float*)d_in[1];   // (128,128,9)
    const float* bias = (const float*)d_in[2];   // (128,)
    float* out = (float*)d_out;

    float* ws  = (float*)d_ws;
    float* m2  = ws;                       // 16*256              = 4096
    float* xs  = ws + 4096;                // 16*128*256          = 524288
    float* Wr  = ws + 528384;              // 128*9*128           = 147456
    float* G   = ws + 675840;              // 16*256*9*128        = 4718592
    int*   idx = (int*)(ws + 5394432);     // 16*4096*9           = 589824
    unsigned short* cand = (unsigned short*)(ws + 5984256);  // 16*4096*16 u16 = 2 MB (~26 MB total)

    k_wr    <<<dim3(576),       dim3(256), 0, stream>>>(w, Wr);
    k_gather<<<dim3(2048),      dim3(256), 0, stream>>>(x, xs);
    k_m2    <<<dim3(16),        dim3(256), 0, stream>>>(xs, m2);
    k_g     <<<dim3(9, 4, 16),  dim3(256), 0, stream>>>(xs, Wr, G);
    k_sel   <<<dim3(128, 16),   dim3(256), 0, stream>>>(x, xs, m2, cand);
    k_ref   <<<dim3(128, 16),   dim3(256), 0, stream>>>(x, xs, m2, cand, idx);
    k_out   <<<dim3(64, 16),    dim3(256), 0, stream>>>(G, idx, bias, out);
}